// Round 1
// baseline (1296.940 us; speedup 1.0000x reference)
//
#include <hip/hip_runtime.h>
#include <hip/hip_bf16.h>
#include <math.h>

#define BATCH   1024
#define SEQ     80
#define EMB     512
#define UNITS   512
#define NBG     64           // batch groups (16 rows each)
#define NCG     4            // col groups (128 cols each); siblings = blockIdx +-64 -> same XCD
#define ROWS    16
#define COLS    128
#define THREADS 512          // 8 waves; wave w owns col tile [cg*128 + w*16, +16)
#define LDW     1544         // LDS row stride (ushort): 1536 + 8 pad

#define H0_OFF   (2u * 1024 * 1024)
#define H1_OFF   (4u * 1024 * 1024)
#define FLAG_OFF (6u * 1024 * 1024)

typedef __attribute__((ext_vector_type(8))) short              bf16x8;
typedef __attribute__((ext_vector_type(8))) unsigned short     u16x8;
typedef __attribute__((ext_vector_type(4))) float              f32x4;
typedef __attribute__((ext_vector_type(2))) unsigned long long u64x2;

__device__ inline unsigned short f2bf(float f) {
    __hip_bfloat16 h = __float2bfloat16(f);
    return *reinterpret_cast<unsigned short*>(&h);
}
__device__ inline float bf2f(unsigned short u) {
    unsigned int x = ((unsigned int)u) << 16;
    return __uint_as_float(x);
}
__device__ inline float tanh_fast(float x) {
    float e = __expf(2.f * x);
    return 1.f - 2.f / (e + 1.f);
}
__device__ inline u16x8 pack8(float4 p0, float4 p1) {
    u16x8 v;
    v[0]=f2bf(p0.x); v[1]=f2bf(p0.y); v[2]=f2bf(p0.z); v[3]=f2bf(p0.w);
    v[4]=f2bf(p1.x); v[5]=f2bf(p1.y); v[6]=f2bf(p1.z); v[7]=f2bf(p1.w);
    return v;
}

// ---------------------------------------------------------------------------
// Pack weights into per-(phase, cg, wave) contiguous B-fragment slabs, bf16.
// slab id g = ((p*NCG + cg)*8 + w)*32 + k0 ; elem = g*512 + lane*8 + j
// value = Wp[k0*32 + (lane>>4)*8 + j][cg*128 + w*16 + (lane&15)]
// Wp rows: [Wx ; Wh] stacked (K=1024).
// ---------------------------------------------------------------------------
__global__ __launch_bounds__(256) void pack_weights(
    const float* __restrict__ W0x, const float* __restrict__ W0h,
    const float* __restrict__ W1x, const float* __restrict__ W1h,
    unsigned short* __restrict__ wpack)
{
    int g    = blockIdx.x * 4 + (threadIdx.x >> 6);   // 0..2047
    int lane = threadIdx.x & 63;
    int p    = g >> 10;
    int cg   = (g >> 8) & 3;
    int w    = (g >> 5) & 7;
    int k0   = g & 31;
    int n    = cg * COLS + w * 16 + (lane & 15);
    int kb   = k0 * 32 + (lane >> 4) * 8;
    const float* Wx = p ? W1x : W0x;
    const float* Wh = p ? W1h : W0h;

    u16x8 v;
#pragma unroll
    for (int j = 0; j < 8; ++j) {
        int k = kb + j;
        float f = (k < 512) ? Wx[(size_t)k * UNITS + n]
                            : Wh[(size_t)(k - 512) * UNITS + n];
        v[j] = f2bf(f);
    }
    *(u16x8*)(wpack + (size_t)g * 512 + lane * 8) = v;
}

// K=512 half with B-slabs streamed from L2 (depth-8 prefetch); off-critical-path
#define RUN_HALF_STREAM(ACC, KBASE, WB)                                        \
    do {                                                                       \
        const unsigned short* a_lds = hcat + abase + (KBASE);                  \
        bf16x8 Bf[8];                                                          \
        _Pragma("unroll")                                                      \
        for (int i = 0; i < 8; ++i)                                            \
            Bf[i] = *(const bf16x8*)((WB) + (size_t)i * 512);                  \
        _Pragma("unroll")                                                      \
        for (int k0 = 0; k0 < 16; ++k0) {                                      \
            bf16x8 a = *(const bf16x8*)(a_lds + k0 * 32);                      \
            bf16x8 b = Bf[k0 & 7];                                             \
            if (k0 + 8 < 16)                                                   \
                Bf[k0 & 7] = *(const bf16x8*)((WB) + (size_t)(k0 + 8) * 512);  \
            ACC = __builtin_amdgcn_mfma_f32_16x16x32_bf16(a, b, ACC, 0, 0, 0); \
        }                                                                      \
    } while (0)

// K=512 half with B held in VGPRs (zero B-load latency); recurrence-critical
#define RUN_HALF_REG(ACC, KBASE, BR)                                           \
    do {                                                                       \
        const unsigned short* a_lds = hcat + abase + (KBASE);                  \
        _Pragma("unroll")                                                      \
        for (int k0 = 0; k0 < 16; ++k0) {                                      \
            bf16x8 a = *(const bf16x8*)(a_lds + k0 * 32);                      \
            ACC = __builtin_amdgcn_mfma_f32_16x16x32_bf16(a, (BR)[k0], ACC, 0, 0, 0); \
        }                                                                      \
    } while (0)

// ---------------------------------------------------------------------------
// 256 blocks = 64 bg x 4 cg, all co-resident (1/CU). Per block: 16 rows,
// 128 cols. LDS A rows: [ x | h0 | h1 ] bf16.
// Split-K schedule: the dependency-free halves (x@W0x, h1@W1h) run inside
// the flag-wait shadows; only 16-MFMA register-B chains sit between syncs.
// W0h and W1x B-fragments live in VGPRs for the whole kernel (128 VGPRs).
// Barrier/flag protocol identical to the validated version.
// ---------------------------------------------------------------------------
__global__ __launch_bounds__(THREADS, 1) void rnn_ex_kernel(
    const int*   __restrict__ inputs,
    const float* __restrict__ emb,
    const float* __restrict__ b0,
    const float* __restrict__ b1,
    const unsigned short* __restrict__ wpack,
    unsigned short* __restrict__ h0buf,   // [2][1024][512] bf16
    unsigned short* __restrict__ h1buf,   // [2][1024][512] bf16
    int* __restrict__ flag0,              // [64][4]
    int* __restrict__ flag1,              // [64][4]
    const float* __restrict__ Wout,
    const float* __restrict__ bout,
    float*       __restrict__ out)
{
    __shared__ __align__(16) unsigned short hcat[ROWS * LDW];

    const int tid   = threadIdx.x;
    const int w     = tid >> 6;
    const int lane  = tid & 63;
    const int quad  = lane >> 4;
    const int l15   = lane & 15;
    const int cg    = blockIdx.x >> 6;    // 0..3
    const int bg    = blockIdx.x & 63;    // 0..63
    const int rbase = bg * ROWS;

    // staging/gather coords: wave w handles rows w and w+8; 16B col units
    // (16B units -> 2-way LDS bank pattern = free, vs 32B/lane 8-way before)
    const int gr = w;                     // row w and w+8
    const int gc = (tid & 63) * 8;        // ushort col of this thread's 16B unit

    // zero h0,h1 (cols 512..1535)
    for (int i = tid; i < ROWS * 1024; i += THREADS) {
        int r = i >> 10, c = i & 1023;
        hcat[r * LDW + 512 + c] = 0;
    }

    // stage x_0
    {
        int ia = inputs[(rbase + gr) * SEQ + 0];
        int ib = inputs[(rbase + gr + 8) * SEQ + 0];
        const float4* ea = (const float4*)(emb + (size_t)ia * EMB + gc);
        const float4* eb = (const float4*)(emb + (size_t)ib * EMB + gc);
        float4 f0 = ea[0], f1 = ea[1], f2 = eb[0], f3 = eb[1];
        *(u16x8*)(hcat + gr * LDW + gc)       = pack8(f0, f1);
        *(u16x8*)(hcat + (gr + 8) * LDW + gc) = pack8(f2, f3);
    }
    __syncthreads();

    const int   mycol = cg * COLS + w * 16 + l15;
    const float bias0 = b0[mycol];
    const float bias1 = b1[mycol];

    const unsigned short* wb0  = wpack + ((size_t)(cg * 256 + w * 32)) * 512 + lane * 8;
    const unsigned short* wb1  = wb0 + (size_t)1024 * 512;   // phase-1 pack half
    const unsigned short* wb0x = wb0;                        // slabs 0..15 : W0x
    const unsigned short* wb1h = wb1 + (size_t)16 * 512;     // slabs 16..31: W1h

    const int abase = l15 * LDW + quad * 8;
    const int fl    = bg * NCG;

    // pin critical-path weights in registers: W0h (phase0 slabs 16..31),
    // W1x (phase1 slabs 0..15). 32 x bf16x8 = 128 VGPRs, static indexing only.
    bf16x8 BH0[16], BX1[16];
#pragma unroll
    for (int i = 0; i < 16; ++i)
        BH0[i] = *(const bf16x8*)(wb0 + (size_t)(16 + i) * 512);
#pragma unroll
    for (int i = 0; i < 16; ++i)
        BX1[i] = *(const bf16x8*)(wb1 + (size_t)i * 512);

    // accX = b0 + x_0 @ W0x
    f32x4 accX = {bias0, bias0, bias0, bias0};
    RUN_HALF_STREAM(accX, 0, wb0x);

    for (int t = 0; t < SEQ; ++t) {
        const int par = t & 1;
        const int tgt = t + 1;

        // ---- phase-1 critical: pre0 = accX + h0(t-1) @ W0h (reg-B) ----
        f32x4 acc = accX;
        RUN_HALF_REG(acc, 512, BH0);
        {
            unsigned short* dst = h0buf +
                ((size_t)par * BATCH + rbase + quad * 4) * UNITS + mycol;
#pragma unroll
            for (int i = 0; i < 4; ++i)
                __hip_atomic_store(dst + (size_t)i * UNITS,
                                   f2bf(tanh_fast(acc[i])),
                                   __ATOMIC_RELAXED, __HIP_MEMORY_SCOPE_AGENT);
        }
        __syncthreads();                                                  // B1
        if (tid == 0)
            __hip_atomic_store(&flag0[fl + cg], tgt,
                               __ATOMIC_RELEASE, __HIP_MEMORY_SCOPE_AGENT);

        // ---- shadow A (hides flag0 RT): x_{t+1} fetch + h1(t-1)@W1h ----
        int tn = (t + 1 < SEQ) ? t + 1 : t;
        int ia = inputs[(rbase + gr) * SEQ + tn];
        int ib = inputs[(rbase + gr + 8) * SEQ + tn];
        const float4* ea = (const float4*)(emb + (size_t)ia * EMB + gc);
        const float4* eb = (const float4*)(emb + (size_t)ib * EMB + gc);
        float4 f0 = ea[0], f1 = ea[1], f2 = eb[0], f3 = eb[1];

        f32x4 accH1 = {bias1, bias1, bias1, bias1};
        RUN_HALF_STREAM(accH1, 1024, wb1h);

        // x_{t+1} -> LDS cols 0..511 (old x readers all finished before B1;
        // new readers run after B4, so B2 orders these writes for them)
        *(u16x8*)(hcat + gr * LDW + gc)       = pack8(f0, f1);
        *(u16x8*)(hcat + (gr + 8) * LDW + gc) = pack8(f2, f3);

        if (tid < NCG)
            while (__hip_atomic_load(&flag0[fl + tid],
                                     __ATOMIC_RELAXED, __HIP_MEMORY_SCOPE_AGENT) < tgt)
                __builtin_amdgcn_s_sleep(1);
        __asm__ volatile("" ::: "memory");
        __syncthreads();                                                  // B2
        {
            // gather full h0' [16x512] -> LDS cols 512..1023 (16B units)
            const unsigned long long* src = (const unsigned long long*)
                (h0buf + ((size_t)par * BATCH + rbase) * UNITS);
            int ua = gr * 128 + (tid & 63) * 2;
            int ub = ua + 8 * 128;
            unsigned long long q0 = __hip_atomic_load(src + ua,     __ATOMIC_RELAXED, __HIP_MEMORY_SCOPE_AGENT);
            unsigned long long q1 = __hip_atomic_load(src + ua + 1, __ATOMIC_RELAXED, __HIP_MEMORY_SCOPE_AGENT);
            unsigned long long q2 = __hip_atomic_load(src + ub,     __ATOMIC_RELAXED, __HIP_MEMORY_SCOPE_AGENT);
            unsigned long long q3 = __hip_atomic_load(src + ub + 1, __ATOMIC_RELAXED, __HIP_MEMORY_SCOPE_AGENT);
            u64x2 wlo; wlo[0] = q0; wlo[1] = q1;
            u64x2 whi; whi[0] = q2; whi[1] = q3;
            *(u64x2*)(hcat + gr * LDW + 512 + gc)       = wlo;
            *(u64x2*)(hcat + (gr + 8) * LDW + 512 + gc) = whi;
        }
        __syncthreads();                                                  // B3

        // ---- phase-2 critical: pre1 = accH1 + h0'(t) @ W1x (reg-B) ----
        f32x4 acc2 = accH1;
        RUN_HALF_REG(acc2, 512, BX1);
        {
            unsigned short* dst = h1buf +
                ((size_t)par * BATCH + rbase + quad * 4) * UNITS + mycol;
#pragma unroll
            for (int i = 0; i < 4; ++i)
                __hip_atomic_store(dst + (size_t)i * UNITS,
                                   f2bf(tanh_fast(acc2[i])),
                                   __ATOMIC_RELAXED, __HIP_MEMORY_SCOPE_AGENT);
        }
        __syncthreads();                                                  // B4
        if (tid == 0)
            __hip_atomic_store(&flag1[fl + cg], tgt,
                               __ATOMIC_RELEASE, __HIP_MEMORY_SCOPE_AGENT);

        // ---- shadow B (hides flag1 RT): accX = b0 + x_{t+1} @ W0x ----
        // x_{t+1} LDS writes happened before B2; reads here are after B4.
        if (t + 1 < SEQ) {
            accX[0] = bias0; accX[1] = bias0; accX[2] = bias0; accX[3] = bias0;
            RUN_HALF_STREAM(accX, 0, wb0x);
        }

        if (tid < NCG)
            while (__hip_atomic_load(&flag1[fl + tid],
                                     __ATOMIC_RELAXED, __HIP_MEMORY_SCOPE_AGENT) < tgt)
                __builtin_amdgcn_s_sleep(1);
        __asm__ volatile("" ::: "memory");
        __syncthreads();                                                  // B5
        {
            // gather full h1' -> LDS cols 1024..1535
            const unsigned long long* src = (const unsigned long long*)
                (h1buf + ((size_t)par * BATCH + rbase) * UNITS);
            int ua = gr * 128 + (tid & 63) * 2;
            int ub = ua + 8 * 128;
            unsigned long long q0 = __hip_atomic_load(src + ua,     __ATOMIC_RELAXED, __HIP_MEMORY_SCOPE_AGENT);
            unsigned long long q1 = __hip_atomic_load(src + ua + 1, __ATOMIC_RELAXED, __HIP_MEMORY_SCOPE_AGENT);
            unsigned long long q2 = __hip_atomic_load(src + ub,     __ATOMIC_RELAXED, __HIP_MEMORY_SCOPE_AGENT);
            unsigned long long q3 = __hip_atomic_load(src + ub + 1, __ATOMIC_RELAXED, __HIP_MEMORY_SCOPE_AGENT);
            u64x2 wlo; wlo[0] = q0; wlo[1] = q1;
            u64x2 whi; whi[0] = q2; whi[1] = q3;
            *(u64x2*)(hcat + gr * LDW + 1024 + gc)       = wlo;
            *(u64x2*)(hcat + (gr + 8) * LDW + 1024 + gc) = whi;
        }
        // no trailing barrier: next-step B1 orders these writes ahead of the
        // next shadow-A reads; phase 1 never touches cols 1024+.
    }
    __syncthreads();

    // ---- epilogue: out = sigmoid(h1 @ Wout + bout); cg 0 blocks only ----
    if (cg == 0) {
#pragma unroll
        for (int rr = 0; rr < 2; ++rr) {
            int r = w * 2 + rr;
            float s = 0.f;
#pragma unroll
            for (int j = 0; j < 8; ++j) {
                int c = lane + 64 * j;
                s += bf2f(hcat[r * LDW + 1024 + c]) * Wout[c];
            }
#pragma unroll
            for (int off = 32; off > 0; off >>= 1) s += __shfl_down(s, off);
            if (lane == 0) {
                float z = s + bout[0];
                out[rbase + r] = 1.f / (1.f + __expf(-z));
            }
        }
    }
}

extern "C" void kernel_launch(void* const* d_in, const int* in_sizes, int n_in,
                              void* d_out, int out_size, void* d_ws, size_t ws_size,
                              hipStream_t stream) {
    const int*   inputs = (const int*)d_in[0];
    const float* emb    = (const float*)d_in[1];
    const float* W0x    = (const float*)d_in[2];
    const float* W0h    = (const float*)d_in[3];
    const float* b0     = (const float*)d_in[4];
    const float* W1x    = (const float*)d_in[5];
    const float* W1h    = (const float*)d_in[6];
    const float* b1     = (const float*)d_in[7];
    const float* Wout   = (const float*)d_in[8];
    const float* bout   = (const float*)d_in[9];
    float*       out    = (float*)d_out;

    unsigned short* wpack = (unsigned short*)d_ws;                      // 2 MB
    unsigned short* h0buf = (unsigned short*)((char*)d_ws + H0_OFF);    // 2 MB
    unsigned short* h1buf = (unsigned short*)((char*)d_ws + H1_OFF);    // 2 MB
    int* flag0 = (int*)((char*)d_ws + FLAG_OFF);                        // 1 KB
    int* flag1 = flag0 + 256;                                           // 1 KB

    hipMemsetAsync((char*)d_ws + FLAG_OFF, 0, 2048, stream);
    pack_weights<<<512, 256, 0, stream>>>(W0x, W0h, W1x, W1h, wpack);
    rnn_ex_kernel<<<NBG * NCG, THREADS, 0, stream>>>(
        inputs, emb, b0, b1, wpack, h0buf, h1buf, flag0, flag1,
        Wout, bout, out);
}